// Round 5
// baseline (22044.760 us; speedup 1.0000x reference)
//
#include <hip/hip_runtime.h>
#include <cmath>

// ---------------------------------------------------------------------------
// RPN head on MI355X. fp32 throughout; conv FMA chain order (ic,ky,kx asc,
// fmaf(w,x,acc)) and the head's 16x16 two-level reduction are bit-exact vs
// the np reference (R1-R4 measured absmax 0.0) — preserve both exactly.
//
// R5: conv restructured as canonical LDS-tiled implicit GEMM.
//   M=256 oc x N=H*W px x K=2304 (k = ic*9 + ky*3 + kx).
//   Block = 256 oc x 64 px; thread = 8 oc x 8 px (acc[8][8]).
//   Per k: 64 FMAs + 2 ds_read_b128 (X from im2col LDS tile) + 2 global
//   dwordx4 (W from L1/L2-hot Wt[k][256]). X tile [9][68] double-buffered,
//   staged with loop-invariant offsets (3 predicated loads/thread/ic).
//   One barrier per ic; no scalar-pipe dependence, no masking VALU ops.
//   Each (oc,px) accumulated by ONE thread over k ascending -> bit-exact.
// ---------------------------------------------------------------------------

#define NTOT_PER_IMG 261888   // sum of H*W*3 over levels
#define ATOT_PER_IMG 4768     // 4*1000 + 768

__constant__ int c_NLVL[5] = {196608, 49152, 12288, 3072, 768};
__constant__ int c_KLVL[5] = {1000, 1000, 1000, 1000, 768};
__constant__ int c_LOFF[5] = {0, 196608, 245760, 258048, 261120};
__constant__ int c_AOFF[5] = {0, 1000, 2000, 3000, 4000};

struct Anch { float cx1[3]; float cy1[3]; };
struct ConvCfg { Anch an[5]; };

// ------------------------------ weight transpose ---------------------------
__global__ __launch_bounds__(256) void wtrans(const float* __restrict__ Wsrc,
                                              float* __restrict__ Wt) {
  __shared__ float T[16][17];
  int k0 = blockIdx.x * 16;   // 2304/16 = 144
  int o0 = blockIdx.y * 16;   // 256/16  = 16
  int i = threadIdx.x >> 4, j = threadIdx.x & 15;
  T[i][j] = Wsrc[(size_t)(o0 + i) * 2304 + (k0 + j)];
  __syncthreads();
  Wt[(size_t)(k0 + i) * 256 + (o0 + j)] = T[j][i];
}

// ------------------------------ fused conv (implicit GEMM) -----------------
// Block tiles: L0 [0,2048) L1 [2048,2560) L2 [2560,2688) L3 [2688,2720)
// L4 [2720,2728); 64 px per tile, all 256 oc per block.
__global__ __launch_bounds__(256, 3) void conv_gemm(
    const float* __restrict__ f0, const float* __restrict__ f1,
    const float* __restrict__ f2, const float* __restrict__ f3,
    const float* __restrict__ f4, const float* __restrict__ Wt,
    const float* __restrict__ convb, const float* __restrict__ clsw,
    const float* __restrict__ clsb, const float* __restrict__ bboxw,
    const float* __restrict__ bboxb, float* __restrict__ scoresOut,
    float4* __restrict__ boxesOut, ConvCfg cfg) {
  __shared__ __align__(16) float s_tl[4096];   // t[16px][256oc] (epilogue)
  __shared__ __align__(16) float s_Xs[1224];   // im2col [2][9][68] dbuf
  __shared__ float s_Red2[272];                // [16][17] head values

  // ---- decode level / image / tile ----
  int b = blockIdx.x;
  const float* feat;
  int lvl, img, tile, H, logW, stride, lvlOff;
  if (b < 2048) {
    lvl = 0; feat = f0; H = 256; logW = 8; stride = 4; lvlOff = 0;
    img = b >> 10; tile = b & 1023;
  } else if (b < 2560) {
    lvl = 1; feat = f1; H = 128; logW = 7; stride = 8; lvlOff = 196608;
    int r = b - 2048; img = r >> 8; tile = r & 255;
  } else if (b < 2688) {
    lvl = 2; feat = f2; H = 64; logW = 6; stride = 16; lvlOff = 245760;
    int r = b - 2560; img = r >> 6; tile = r & 63;
  } else if (b < 2720) {
    lvl = 3; feat = f3; H = 32; logW = 5; stride = 32; lvlOff = 258048;
    int r = b - 2688; img = r >> 4; tile = r & 15;
  } else {
    lvl = 4; feat = f4; H = 16; logW = 4; stride = 64; lvlOff = 261120;
    int r = b - 2720; img = r >> 2; tile = r & 3;
  }
  const int W = H, HW = H * W;
  const int p0 = tile * 64;
  const float* fimg = feat + (size_t)img * 256 * HW;

  const int tid = threadIdx.x;
  const int oc0 = (tid >> 3) * 8;   // 32 oc-groups x 8 oc
  const int pxg = tid & 7;          // 8 px-groups x 8 px
  const int px0 = pxg * 8;

  // ---- staging descriptors (loop-invariant: only ic base advances) ----
  int goff[3], loff[3];
#pragma unroll
  for (int s = 0; s < 3; s++) {
    int idx = tid + s * 256;
    goff[s] = -1; loff[s] = -1;
    if (idx < 576) {
      int t = idx >> 6, j = idx & 63;
      int ky = t / 3, kx = t - ky * 3;
      int pxl = p0 + j;
      int py = pxl >> logW, px = pxl & (W - 1);
      int sy = py + ky - 1, sx = px + kx - 1;
      loff[s] = t * 68 + j;
      if (sy >= 0 && sy < H && sx >= 0 && sx < W) goff[s] = sy * W + sx;
    }
  }

  float acc[8][8];
#pragma unroll
  for (int i = 0; i < 8; i++)
#pragma unroll
    for (int p = 0; p < 8; p++) acc[i][p] = 0.f;

  // ---- stage ic=0 into buffer 0 ----
#pragma unroll
  for (int s = 0; s < 3; s++)
    if (loff[s] >= 0) s_Xs[loff[s]] = (goff[s] >= 0) ? fimg[goff[s]] : 0.f;
  __syncthreads();

  // ---- main K loop: one ic (9 k-steps) per iteration ----
#pragma unroll 1
  for (int ic = 0; ic < 256; ic++) {
    const float* Xc = s_Xs + (ic & 1) * 612;
    float* Xn = s_Xs + ((ic + 1) & 1) * 612;

    // issue next ic's staging loads early (latency hidden under FMAs)
    float sv[3];
    if (ic < 255) {
      const float* fnext = fimg + (size_t)(ic + 1) * HW;
#pragma unroll
      for (int s = 0; s < 3; s++)
        sv[s] = (goff[s] >= 0) ? fnext[goff[s]] : 0.f;
    }

    const float* wbase = Wt + (size_t)ic * 9 * 256 + oc0;
#pragma unroll
    for (int t = 0; t < 9; t++) {
      float4 wa = *(const float4*)(wbase + t * 256);
      float4 wb = *(const float4*)(wbase + t * 256 + 4);
      float4 xa = *(const float4*)(Xc + t * 68 + px0);
      float4 xb = *(const float4*)(Xc + t * 68 + px0 + 4);
      float wv[8] = {wa.x, wa.y, wa.z, wa.w, wb.x, wb.y, wb.z, wb.w};
      float xv[8] = {xa.x, xa.y, xa.z, xa.w, xb.x, xb.y, xb.z, xb.w};
#pragma unroll
      for (int i = 0; i < 8; i++)
#pragma unroll
        for (int p = 0; p < 8; p++)
          acc[i][p] = __builtin_fmaf(wv[i], xv[p], acc[i][p]);
    }

    if (ic < 255) {
#pragma unroll
      for (int s = 0; s < 3; s++)
        if (loff[s] >= 0) Xn[loff[s]] = sv[s];
    }
    __syncthreads();
  }

  // ---- epilogue: 4 rounds of 16 px through s_tl ----
  float cb[8];
#pragma unroll
  for (int i = 0; i < 8; i++) cb[i] = convb[oc0 + i];

  const Anch an = cfg.an[lvl];
  const float BCLIP = (float)4.135166556742356;  // log(1000/16)
  const size_t obase = (size_t)img * NTOT_PER_IMG + lvlOff;

#pragma unroll 1
  for (int r = 0; r < 4; r++) {
    if ((pxg >> 1) == r) {   // this thread's 8 px lie in round r
      int pl = px0 - 16 * r; // 0 or 8
#pragma unroll
      for (int p = 0; p < 8; p++) {
        float4 v0 = make_float4(fmaxf(acc[0][p] + cb[0], 0.f),
                                fmaxf(acc[1][p] + cb[1], 0.f),
                                fmaxf(acc[2][p] + cb[2], 0.f),
                                fmaxf(acc[3][p] + cb[3], 0.f));
        float4 v1 = make_float4(fmaxf(acc[4][p] + cb[4], 0.f),
                                fmaxf(acc[5][p] + cb[5], 0.f),
                                fmaxf(acc[6][p] + cb[6], 0.f),
                                fmaxf(acc[7][p] + cb[7], 0.f));
        *(float4*)(s_tl + (pl + p) * 256 + oc0) = v0;
        *(float4*)(s_tl + (pl + p) * 256 + oc0 + 4) = v1;
      }
    }
    __syncthreads();

    // heads: per (px, c) dot over 256 oc in 16x16 two-level order
    if (tid < 240) {
      int px = tid / 15, c = tid - px * 15;
      const float* wr0 = (c < 3) ? (clsw + c * 256) : (bboxw + (c - 3) * 256);
      float bb = (c < 3) ? clsb[c] : bboxb[c - 3];
      const float* trow = &s_tl[px * 256];
      float tot = 0.f;
#pragma unroll
      for (int g = 0; g < 16; g++) {
        const float* wr = wr0 + g * 16;
        const float* tr = trow + g * 16;
        float s = 0.f;
#pragma unroll
        for (int i = 0; i < 16; i++) s += wr[i] * tr[i];
        tot += s;
      }
      s_Red2[px * 17 + c] = tot + bb;
    }
    __syncthreads();

    // decode: one (pixel, anchor) per thread
    if (tid < 48) {
      int px = tid / 3, a = tid - px * 3;
      int pxl = p0 + r * 16 + px;
      int gy = pxl >> logW, gx = pxl & (W - 1);
      float sc = s_Red2[px * 17 + a];
      float dxv = s_Red2[px * 17 + 3 + a * 4 + 0];
      float dyv = s_Red2[px * 17 + 3 + a * 4 + 1];
      float dwv = s_Red2[px * 17 + 3 + a * 4 + 2];
      float dhv = s_Red2[px * 17 + 3 + a * 4 + 3];
      float sx = (float)(gx * stride), sy = (float)(gy * stride);
      float x1 = __fadd_rn(sx, an.cx1[a]);
      float x2 = __fsub_rn(sx, an.cx1[a]);
      float y1 = __fadd_rn(sy, an.cy1[a]);
      float y2 = __fsub_rn(sy, an.cy1[a]);
      float wdt = __fadd_rn(__fsub_rn(x2, x1), 1.0f);
      float hgt = __fadd_rn(__fsub_rn(y2, y1), 1.0f);
      float ctx = __fadd_rn(x1, __fmul_rn(0.5f, wdt));
      float cty = __fadd_rn(y1, __fmul_rn(0.5f, hgt));
      float dw = fminf(dwv, BCLIP), dh = fminf(dhv, BCLIP);
      float pcx = __fadd_rn(__fmul_rn(dxv, wdt), ctx);
      float pcy = __fadd_rn(__fmul_rn(dyv, hgt), cty);
      float pw = __fmul_rn(expf(dw), wdt);
      float ph = __fmul_rn(expf(dh), hgt);
      float hw = __fmul_rn(0.5f, pw), hh = __fmul_rn(0.5f, ph);
      float bx1 = __fsub_rn(pcx, hw);
      float by1 = __fsub_rn(pcy, hh);
      float bx2 = __fsub_rn(__fadd_rn(pcx, hw), 1.0f);
      float by2 = __fsub_rn(__fadd_rn(pcy, hh), 1.0f);
      bx1 = fminf(fmaxf(bx1, 0.f), 1023.f);
      by1 = fminf(fmaxf(by1, 0.f), 1023.f);
      bx2 = fminf(fmaxf(bx2, 0.f), 1023.f);
      by2 = fminf(fmaxf(by2, 0.f), 1023.f);
      size_t o = obase + (size_t)pxl * 3 + a;
      scoresOut[o] = sc;
      boxesOut[o] = make_float4(bx1, by1, bx2, by2);
    }
    __syncthreads();
  }
}

// ------------------------------ top-k --------------------------------------
__device__ __forceinline__ unsigned fkey(float f) {
  unsigned b = __float_as_uint(f);
  return (b & 0x80000000u) ? ~b : (b | 0x80000000u);
}
__device__ __forceinline__ float funkey(unsigned u) {
  unsigned b = (u & 0x80000000u) ? (u & 0x7fffffffu) : ~u;
  return __uint_as_float(b);
}

// Exact lax.top_k: value desc, index asc on ties. Radix-select the threshold,
// bisect an index cut for boundary ties, bitonic-sort packed (key, ~idx).
template <bool FINAL>
__global__ __launch_bounds__(1024) void topk_kernel(
    const float* __restrict__ scoresIn, const float4* __restrict__ boxesIn,
    float* __restrict__ scoresOut, float4* __restrict__ boxesOut,
    float* __restrict__ finalOut) {
  __shared__ unsigned long long keys[1024];
  __shared__ unsigned hist[256];
  __shared__ unsigned s_comm[4];
  int lvl = 0, img, N, k;
  const float* src;
  const float4* bsrc;
  if (FINAL) {
    img = blockIdx.x; N = ATOT_PER_IMG; k = 1000;
    src = scoresIn + (size_t)img * ATOT_PER_IMG;
    bsrc = boxesIn + (size_t)img * ATOT_PER_IMG;
  } else {
    lvl = blockIdx.x; img = blockIdx.y;
    N = c_NLVL[lvl]; k = c_KLVL[lvl];
    src = scoresIn + (size_t)img * NTOT_PER_IMG + c_LOFF[lvl];
    bsrc = boxesIn + (size_t)img * NTOT_PER_IMG + c_LOFF[lvl];
  }
  const int tid = threadIdx.x;

  unsigned pref = 0, pmask = 0, krem = (unsigned)k, cntT = 0;
  for (int pass = 3; pass >= 0; pass--) {
    int shift = pass * 8;
    if (tid < 256) hist[tid] = 0;
    __syncthreads();
    for (int i = tid; i < N; i += 1024) {
      unsigned u = fkey(src[i]);
      if ((u & pmask) == pref) atomicAdd(&hist[(u >> shift) & 255], 1u);
    }
    __syncthreads();
    if (tid == 0) {
      unsigned cum = 0;
      for (int d = 255; d >= 0; d--) {
        unsigned c = hist[d];
        if (cum + c >= krem) {
          s_comm[0] = krem - cum; s_comm[1] = c; s_comm[2] = (unsigned)d;
          break;
        }
        cum += c;
      }
    }
    __syncthreads();
    krem = s_comm[0]; cntT = s_comm[1];
    pref |= s_comm[2] << shift;
    pmask |= 0xFFu << shift;
    __syncthreads();
  }
  const unsigned T = pref, r = krem;
  unsigned m = (unsigned)N;
  if (r < cntT) {  // boundary ties: smallest r indices among {u == T}
    unsigned lo = 0, hi = (unsigned)N;
    while (lo < hi) {
      unsigned mid = (lo + hi) >> 1;
      if (tid == 0) s_comm[3] = 0;
      __syncthreads();
      for (unsigned i = tid; i < mid; i += 1024)
        if (fkey(src[i]) == T) atomicAdd(&s_comm[3], 1u);
      __syncthreads();
      unsigned c = s_comm[3];
      __syncthreads();
      if (c >= r) hi = mid; else lo = mid + 1;
    }
    m = lo;
  }
  if (tid == 0) s_comm[3] = 0;
  __syncthreads();
  for (int i = tid; i < N; i += 1024) {
    unsigned u = fkey(src[i]);
    if (u > T || (u == T && (unsigned)i < m)) {
      unsigned p = atomicAdd(&s_comm[3], 1u);
      if (p < 1024)
        keys[p] = ((unsigned long long)u << 32) | (unsigned)(~(unsigned)i);
    }
  }
  __syncthreads();
  if (tid >= k) keys[tid] = 0ull;  // pad; sorts to the end
  __syncthreads();
  // bitonic sort, descending
  for (unsigned k2 = 2; k2 <= 1024; k2 <<= 1) {
    for (unsigned j = k2 >> 1; j > 0; j >>= 1) {
      unsigned i = tid, ixj = i ^ j;
      if (ixj > i) {
        unsigned long long a = keys[i], b = keys[ixj];
        bool sw = ((i & k2) == 0) ? (a < b) : (a > b);
        if (sw) { keys[i] = b; keys[ixj] = a; }
      }
      __syncthreads();
    }
  }
  if (tid < k) {
    unsigned long long key = keys[tid];
    unsigned u = (unsigned)(key >> 32);
    unsigned idx = ~((unsigned)key);
    float sc = funkey(u);
    float4 b = bsrc[idx];
    if (FINAL) {
      float* o = finalOut + ((size_t)img * 1000 + tid) * 5;
      o[0] = b.x; o[1] = b.y; o[2] = b.z; o[3] = b.w; o[4] = sc;
    } else {
      scoresOut[(size_t)img * ATOT_PER_IMG + c_AOFF[lvl] + tid] = sc;
      boxesOut[(size_t)img * ATOT_PER_IMG + c_AOFF[lvl] + tid] = b;
    }
  }
}

// ------------------------------ NMS ----------------------------------------
__global__ __launch_bounds__(256) void nms_matrix(
    const float4* __restrict__ allb, unsigned long long* __restrict__ supp) {
  int lvl = blockIdx.x, img = blockIdx.y, rb = blockIdx.z;
  int k = c_KLVL[lvl];
  int task = img * 5 + lvl;
  const float4* src = allb + (size_t)img * ATOT_PER_IMG + c_AOFF[lvl];
  __shared__ float4 bb[1000];
  __shared__ float ar[1000];
  for (int j = threadIdx.x; j < k; j += 256) {
    float4 b = src[j];
    bb[j] = b;
    ar[j] = __fmul_rn(__fsub_rn(b.z, b.x), __fsub_rn(b.w, b.y));
  }
  __syncthreads();
  int i = rb * 256 + threadIdx.x;
  if (i < k) {
    float4 bi = bb[i];
    float ai = ar[i];
    unsigned long long* row = supp + ((size_t)task * 1024 + i) * 16;
    int jw0 = i >> 6;
    for (int jw = 0; jw < jw0; jw++) row[jw] = 0ull;
    for (int jw = jw0; jw < 16; jw++) {
      unsigned long long bits = 0;
      int jbase = jw * 64;
      for (int jj = 0; jj < 64; jj++) {
        int j = jbase + jj;
        if (j > i && j < k) {
          float4 bj = bb[j];
          float ltx = fmaxf(bi.x, bj.x), lty = fmaxf(bi.y, bj.y);
          float rbx = fminf(bi.z, bj.z), rby = fminf(bi.w, bj.w);
          float wx = fmaxf(__fsub_rn(rbx, ltx), 0.f);
          float wy = fmaxf(__fsub_rn(rby, lty), 0.f);
          float inter = __fmul_rn(wx, wy);
          float den = __fadd_rn(__fsub_rn(__fadd_rn(ai, ar[j]), inter), 1e-9f);
          if (__fdiv_rn(inter, den) > 0.7f) bits |= 1ull << jj;
        }
      }
      row[jw] = bits;
    }
  }
}

__global__ __launch_bounds__(64) void nms_scan(
    const float* __restrict__ topS, const unsigned long long* __restrict__ supp,
    float* __restrict__ fscore) {
  int lvl = blockIdx.x, img = blockIdx.y;
  int k = c_KLVL[lvl];
  int task = img * 5 + lvl;
  int lane = threadIdx.x;
  const unsigned long long* base = supp + (size_t)task * 1024 * 16;
  unsigned long long rem = 0, keep = 0;  // lane l<16 holds 64-bit word l
  for (int b0 = 0; b0 < k; b0 += 16) {
    unsigned long long buf[16];
#pragma unroll
    for (int t = 0; t < 16; t++) {
      int i = b0 + t;
      buf[t] = (lane < 16 && i < k) ? base[(size_t)i * 16 + lane] : 0ull;
    }
#pragma unroll
    for (int t = 0; t < 16; t++) {
      int i = b0 + t;
      if (i >= k) break;
      int wi = i >> 6, bi = i & 63;
      unsigned long long rw = __shfl(rem, wi);
      if (!((rw >> bi) & 1ull)) {  // i survives: suppress its row
        rem |= buf[t];
        if (lane == wi) keep |= (1ull << bi);
      }
    }
  }
  const float* ts = topS + (size_t)img * ATOT_PER_IMG + c_AOFF[lvl];
  float* fs = fscore + (size_t)img * ATOT_PER_IMG + c_AOFF[lvl];
  for (int i = lane; i < k; i += 64) {
    int wi = i >> 6;
    unsigned long long kw = __shfl(keep, wi);
    fs[i] = ((kw >> (i & 63)) & 1ull) ? ts[i] : -1e9f;
  }
}

// ------------------------------ host ---------------------------------------
static Anch mkAnch(double size) {
  Anch a;
  const double R[3] = {0.5, 1.0, 2.0};
  for (int i = 0; i < 3; i++) {
    double w = size * sqrt(1.0 / R[i]);
    double h = size * sqrt(R[i]);
    a.cx1[i] = (float)(-w / 2.0);
    a.cy1[i] = (float)(-h / 2.0);
  }
  return a;
}

extern "C" void kernel_launch(void* const* d_in, const int* in_sizes, int n_in,
                              void* d_out, int out_size, void* d_ws,
                              size_t ws_size, hipStream_t stream) {
  (void)in_sizes; (void)n_in; (void)out_size; (void)ws_size;
  const float* f0 = (const float*)d_in[0];
  const float* f1 = (const float*)d_in[1];
  const float* f2 = (const float*)d_in[2];
  const float* f3 = (const float*)d_in[3];
  const float* f4 = (const float*)d_in[4];
  const float* conv_w = (const float*)d_in[5];
  const float* conv_b = (const float*)d_in[6];
  const float* cls_w  = (const float*)d_in[7];
  const float* cls_b  = (const float*)d_in[8];
  const float* bbox_w = (const float*)d_in[9];
  const float* bbox_b = (const float*)d_in[10];
  float* out = (float*)d_out;

  // workspace layout (floats), all 16B-aligned; total ~14.4 MB
  float* wsf = (float*)d_ws;
  float* Wt     = wsf;                      // 589824
  float* scores = Wt + 589824;              // 2*261888
  float* boxes  = scores + 2 * NTOT_PER_IMG;       // 2*261888*4
  float* topS   = boxes + (size_t)2 * NTOT_PER_IMG * 4;  // 2*4768
  float* allb   = topS + 2 * ATOT_PER_IMG;         // 2*4768*4
  float* fscore = allb + (size_t)2 * ATOT_PER_IMG * 4;   // 2*4768
  unsigned long long* supp =
      (unsigned long long*)(fscore + 2 * ATOT_PER_IMG);  // 10*1024*16 u64

  wtrans<<<dim3(144, 16), 256, 0, stream>>>(conv_w, Wt);

  ConvCfg cfg;
  const double SZ[5] = {32, 64, 128, 256, 512};
  for (int l = 0; l < 5; l++) cfg.an[l] = mkAnch(SZ[l]);

  conv_gemm<<<2728, 256, 0, stream>>>(f0, f1, f2, f3, f4, Wt, conv_b, cls_w,
                                      cls_b, bbox_w, bbox_b, scores,
                                      (float4*)boxes, cfg);

  topk_kernel<false><<<dim3(5, 2), 1024, 0, stream>>>(
      scores, (const float4*)boxes, topS, (float4*)allb, nullptr);
  nms_matrix<<<dim3(5, 2, 4), 256, 0, stream>>>((const float4*)allb, supp);
  nms_scan<<<dim3(5, 2), 64, 0, stream>>>(topS, supp, fscore);
  topk_kernel<true><<<2, 1024, 0, stream>>>(
      fscore, (const float4*)allb, nullptr, nullptr, out);
}

// Round 6
// 3697.139 us; speedup vs baseline: 5.9627x; 5.9627x over previous
//
#include <hip/hip_runtime.h>
#include <cmath>

// ---------------------------------------------------------------------------
// RPN head on MI355X. fp32 throughout; conv FMA chain order (ic,ky,kx asc,
// fmaf(w,x,acc)) and the head's 16x16 two-level reduction are bit-exact vs
// the np reference (R1-R5 measured absmax 0.0) — preserve both exactly.
//
// R6 = R5 (implicit GEMM, 256oc x 64px block, 8oc x 8px/thread) with the
// accumulator spill fixed. R5 evidence: WRITE_SIZE 65 GB / FETCH 36 GB /
// VGPR 84 / VALUBusy 6% -> acc[8][8] spilled to scratch because the fully
// unrolled 9-step k-loop hoisted 18 dwordx4 loads (72 VGPRs) under a 170-reg
// launch_bounds cap. Fix:
//   - __launch_bounds__(256,2): cap 256 regs (non-forcing; HW occupancy
//     still follows actual usage)
//   - #pragma unroll 3 on the t-loop: <=6 loads (24 regs) in flight
// ---------------------------------------------------------------------------

#define NTOT_PER_IMG 261888   // sum of H*W*3 over levels
#define ATOT_PER_IMG 4768     // 4*1000 + 768

__constant__ int c_NLVL[5] = {196608, 49152, 12288, 3072, 768};
__constant__ int c_KLVL[5] = {1000, 1000, 1000, 1000, 768};
__constant__ int c_LOFF[5] = {0, 196608, 245760, 258048, 261120};
__constant__ int c_AOFF[5] = {0, 1000, 2000, 3000, 4000};

struct Anch { float cx1[3]; float cy1[3]; };
struct ConvCfg { Anch an[5]; };

// ------------------------------ weight transpose ---------------------------
__global__ __launch_bounds__(256) void wtrans(const float* __restrict__ Wsrc,
                                              float* __restrict__ Wt) {
  __shared__ float T[16][17];
  int k0 = blockIdx.x * 16;   // 2304/16 = 144
  int o0 = blockIdx.y * 16;   // 256/16  = 16
  int i = threadIdx.x >> 4, j = threadIdx.x & 15;
  T[i][j] = Wsrc[(size_t)(o0 + i) * 2304 + (k0 + j)];
  __syncthreads();
  Wt[(size_t)(k0 + i) * 256 + (o0 + j)] = T[j][i];
}

// ------------------------------ fused conv (implicit GEMM) -----------------
// Block tiles: L0 [0,2048) L1 [2048,2560) L2 [2560,2688) L3 [2688,2720)
// L4 [2720,2728); 64 px per tile, all 256 oc per block.
__global__ __launch_bounds__(256, 2) void conv_gemm(
    const float* __restrict__ f0, const float* __restrict__ f1,
    const float* __restrict__ f2, const float* __restrict__ f3,
    const float* __restrict__ f4, const float* __restrict__ Wt,
    const float* __restrict__ convb, const float* __restrict__ clsw,
    const float* __restrict__ clsb, const float* __restrict__ bboxw,
    const float* __restrict__ bboxb, float* __restrict__ scoresOut,
    float4* __restrict__ boxesOut, ConvCfg cfg) {
  __shared__ __align__(16) float s_tl[4096];   // t[16px][256oc] (epilogue)
  __shared__ __align__(16) float s_Xs[1224];   // im2col [2][9][68] dbuf
  __shared__ float s_Red2[272];                // [16][17] head values

  // ---- decode level / image / tile ----
  int b = blockIdx.x;
  const float* feat;
  int lvl, img, tile, H, logW, stride, lvlOff;
  if (b < 2048) {
    lvl = 0; feat = f0; H = 256; logW = 8; stride = 4; lvlOff = 0;
    img = b >> 10; tile = b & 1023;
  } else if (b < 2560) {
    lvl = 1; feat = f1; H = 128; logW = 7; stride = 8; lvlOff = 196608;
    int r = b - 2048; img = r >> 8; tile = r & 255;
  } else if (b < 2688) {
    lvl = 2; feat = f2; H = 64; logW = 6; stride = 16; lvlOff = 245760;
    int r = b - 2560; img = r >> 6; tile = r & 63;
  } else if (b < 2720) {
    lvl = 3; feat = f3; H = 32; logW = 5; stride = 32; lvlOff = 258048;
    int r = b - 2688; img = r >> 4; tile = r & 15;
  } else {
    lvl = 4; feat = f4; H = 16; logW = 4; stride = 64; lvlOff = 261120;
    int r = b - 2720; img = r >> 2; tile = r & 3;
  }
  const int W = H, HW = H * W;
  const int p0 = tile * 64;
  const float* fimg = feat + (size_t)img * 256 * HW;

  const int tid = threadIdx.x;
  const int oc0 = (tid >> 3) * 8;   // 32 oc-groups x 8 oc
  const int pxg = tid & 7;          // 8 px-groups x 8 px
  const int px0 = pxg * 8;

  // ---- staging descriptors (loop-invariant: only ic base advances) ----
  int goff[3], loff[3];
#pragma unroll
  for (int s = 0; s < 3; s++) {
    int idx = tid + s * 256;
    goff[s] = -1; loff[s] = -1;
    if (idx < 576) {
      int t = idx >> 6, j = idx & 63;
      int ky = t / 3, kx = t - ky * 3;
      int pxl = p0 + j;
      int py = pxl >> logW, px = pxl & (W - 1);
      int sy = py + ky - 1, sx = px + kx - 1;
      loff[s] = t * 68 + j;
      if (sy >= 0 && sy < H && sx >= 0 && sx < W) goff[s] = sy * W + sx;
    }
  }

  float acc[8][8];
#pragma unroll
  for (int i = 0; i < 8; i++)
#pragma unroll
    for (int p = 0; p < 8; p++) acc[i][p] = 0.f;

  // ---- stage ic=0 into buffer 0 ----
#pragma unroll
  for (int s = 0; s < 3; s++)
    if (loff[s] >= 0) s_Xs[loff[s]] = (goff[s] >= 0) ? fimg[goff[s]] : 0.f;
  __syncthreads();

  // ---- main K loop: one ic (9 k-steps) per iteration ----
#pragma unroll 1
  for (int ic = 0; ic < 256; ic++) {
    const float* Xc = s_Xs + (ic & 1) * 612;
    float* Xn = s_Xs + ((ic + 1) & 1) * 612;

    // issue next ic's staging loads early (latency hidden under FMAs)
    float sv[3];
    if (ic < 255) {
      const float* fnext = fimg + (size_t)(ic + 1) * HW;
#pragma unroll
      for (int s = 0; s < 3; s++)
        sv[s] = (goff[s] >= 0) ? fnext[goff[s]] : 0.f;
    }

    const float* wbase = Wt + (size_t)ic * 9 * 256 + oc0;
    // unroll 3: at most 6 dwordx4 loads (24 VGPRs) in flight -> no spill
#pragma unroll 3
    for (int t = 0; t < 9; t++) {
      float4 wa = *(const float4*)(wbase + t * 256);
      float4 wb = *(const float4*)(wbase + t * 256 + 4);
      float4 xa = *(const float4*)(Xc + t * 68 + px0);
      float4 xb = *(const float4*)(Xc + t * 68 + px0 + 4);
      float wv[8] = {wa.x, wa.y, wa.z, wa.w, wb.x, wb.y, wb.z, wb.w};
      float xv[8] = {xa.x, xa.y, xa.z, xa.w, xb.x, xb.y, xb.z, xb.w};
#pragma unroll
      for (int i = 0; i < 8; i++)
#pragma unroll
        for (int p = 0; p < 8; p++)
          acc[i][p] = __builtin_fmaf(wv[i], xv[p], acc[i][p]);
    }

    if (ic < 255) {
#pragma unroll
      for (int s = 0; s < 3; s++)
        if (loff[s] >= 0) Xn[loff[s]] = sv[s];
    }
    __syncthreads();
  }

  // ---- epilogue: 4 rounds of 16 px through s_tl ----
  float cb[8];
#pragma unroll
  for (int i = 0; i < 8; i++) cb[i] = convb[oc0 + i];

  const Anch an = cfg.an[lvl];
  const float BCLIP = (float)4.135166556742356;  // log(1000/16)
  const size_t obase = (size_t)img * NTOT_PER_IMG + lvlOff;

#pragma unroll 1
  for (int r = 0; r < 4; r++) {
    if ((pxg >> 1) == r) {   // this thread's 8 px lie in round r
      int pl = px0 - 16 * r; // 0 or 8
#pragma unroll
      for (int p = 0; p < 8; p++) {
        float4 v0 = make_float4(fmaxf(acc[0][p] + cb[0], 0.f),
                                fmaxf(acc[1][p] + cb[1], 0.f),
                                fmaxf(acc[2][p] + cb[2], 0.f),
                                fmaxf(acc[3][p] + cb[3], 0.f));
        float4 v1 = make_float4(fmaxf(acc[4][p] + cb[4], 0.f),
                                fmaxf(acc[5][p] + cb[5], 0.f),
                                fmaxf(acc[6][p] + cb[6], 0.f),
                                fmaxf(acc[7][p] + cb[7], 0.f));
        *(float4*)(s_tl + (pl + p) * 256 + oc0) = v0;
        *(float4*)(s_tl + (pl + p) * 256 + oc0 + 4) = v1;
      }
    }
    __syncthreads();

    // heads: per (px, c) dot over 256 oc in 16x16 two-level order
    if (tid < 240) {
      int px = tid / 15, c = tid - px * 15;
      const float* wr0 = (c < 3) ? (clsw + c * 256) : (bboxw + (c - 3) * 256);
      float bb = (c < 3) ? clsb[c] : bboxb[c - 3];
      const float* trow = &s_tl[px * 256];
      float tot = 0.f;
#pragma unroll
      for (int g = 0; g < 16; g++) {
        const float* wr = wr0 + g * 16;
        const float* tr = trow + g * 16;
        float s = 0.f;
#pragma unroll
        for (int i = 0; i < 16; i++) s += wr[i] * tr[i];
        tot += s;
      }
      s_Red2[px * 17 + c] = tot + bb;
    }
    __syncthreads();

    // decode: one (pixel, anchor) per thread
    if (tid < 48) {
      int px = tid / 3, a = tid - px * 3;
      int pxl = p0 + r * 16 + px;
      int gy = pxl >> logW, gx = pxl & (W - 1);
      float sc = s_Red2[px * 17 + a];
      float dxv = s_Red2[px * 17 + 3 + a * 4 + 0];
      float dyv = s_Red2[px * 17 + 3 + a * 4 + 1];
      float dwv = s_Red2[px * 17 + 3 + a * 4 + 2];
      float dhv = s_Red2[px * 17 + 3 + a * 4 + 3];
      float sx = (float)(gx * stride), sy = (float)(gy * stride);
      float x1 = __fadd_rn(sx, an.cx1[a]);
      float x2 = __fsub_rn(sx, an.cx1[a]);
      float y1 = __fadd_rn(sy, an.cy1[a]);
      float y2 = __fsub_rn(sy, an.cy1[a]);
      float wdt = __fadd_rn(__fsub_rn(x2, x1), 1.0f);
      float hgt = __fadd_rn(__fsub_rn(y2, y1), 1.0f);
      float ctx = __fadd_rn(x1, __fmul_rn(0.5f, wdt));
      float cty = __fadd_rn(y1, __fmul_rn(0.5f, hgt));
      float dw = fminf(dwv, BCLIP), dh = fminf(dhv, BCLIP);
      float pcx = __fadd_rn(__fmul_rn(dxv, wdt), ctx);
      float pcy = __fadd_rn(__fmul_rn(dyv, hgt), cty);
      float pw = __fmul_rn(expf(dw), wdt);
      float ph = __fmul_rn(expf(dh), hgt);
      float hw = __fmul_rn(0.5f, pw), hh = __fmul_rn(0.5f, ph);
      float bx1 = __fsub_rn(pcx, hw);
      float by1 = __fsub_rn(pcy, hh);
      float bx2 = __fsub_rn(__fadd_rn(pcx, hw), 1.0f);
      float by2 = __fsub_rn(__fadd_rn(pcy, hh), 1.0f);
      bx1 = fminf(fmaxf(bx1, 0.f), 1023.f);
      by1 = fminf(fmaxf(by1, 0.f), 1023.f);
      bx2 = fminf(fmaxf(bx2, 0.f), 1023.f);
      by2 = fminf(fmaxf(by2, 0.f), 1023.f);
      size_t o = obase + (size_t)pxl * 3 + a;
      scoresOut[o] = sc;
      boxesOut[o] = make_float4(bx1, by1, bx2, by2);
    }
    __syncthreads();
  }
}

// ------------------------------ top-k --------------------------------------
__device__ __forceinline__ unsigned fkey(float f) {
  unsigned b = __float_as_uint(f);
  return (b & 0x80000000u) ? ~b : (b | 0x80000000u);
}
__device__ __forceinline__ float funkey(unsigned u) {
  unsigned b = (u & 0x80000000u) ? (u & 0x7fffffffu) : ~u;
  return __uint_as_float(b);
}

// Exact lax.top_k: value desc, index asc on ties. Radix-select the threshold,
// bisect an index cut for boundary ties, bitonic-sort packed (key, ~idx).
template <bool FINAL>
__global__ __launch_bounds__(1024) void topk_kernel(
    const float* __restrict__ scoresIn, const float4* __restrict__ boxesIn,
    float* __restrict__ scoresOut, float4* __restrict__ boxesOut,
    float* __restrict__ finalOut) {
  __shared__ unsigned long long keys[1024];
  __shared__ unsigned hist[256];
  __shared__ unsigned s_comm[4];
  int lvl = 0, img, N, k;
  const float* src;
  const float4* bsrc;
  if (FINAL) {
    img = blockIdx.x; N = ATOT_PER_IMG; k = 1000;
    src = scoresIn + (size_t)img * ATOT_PER_IMG;
    bsrc = boxesIn + (size_t)img * ATOT_PER_IMG;
  } else {
    lvl = blockIdx.x; img = blockIdx.y;
    N = c_NLVL[lvl]; k = c_KLVL[lvl];
    src = scoresIn + (size_t)img * NTOT_PER_IMG + c_LOFF[lvl];
    bsrc = boxesIn + (size_t)img * NTOT_PER_IMG + c_LOFF[lvl];
  }
  const int tid = threadIdx.x;

  unsigned pref = 0, pmask = 0, krem = (unsigned)k, cntT = 0;
  for (int pass = 3; pass >= 0; pass--) {
    int shift = pass * 8;
    if (tid < 256) hist[tid] = 0;
    __syncthreads();
    for (int i = tid; i < N; i += 1024) {
      unsigned u = fkey(src[i]);
      if ((u & pmask) == pref) atomicAdd(&hist[(u >> shift) & 255], 1u);
    }
    __syncthreads();
    if (tid == 0) {
      unsigned cum = 0;
      for (int d = 255; d >= 0; d--) {
        unsigned c = hist[d];
        if (cum + c >= krem) {
          s_comm[0] = krem - cum; s_comm[1] = c; s_comm[2] = (unsigned)d;
          break;
        }
        cum += c;
      }
    }
    __syncthreads();
    krem = s_comm[0]; cntT = s_comm[1];
    pref |= s_comm[2] << shift;
    pmask |= 0xFFu << shift;
    __syncthreads();
  }
  const unsigned T = pref, r = krem;
  unsigned m = (unsigned)N;
  if (r < cntT) {  // boundary ties: smallest r indices among {u == T}
    unsigned lo = 0, hi = (unsigned)N;
    while (lo < hi) {
      unsigned mid = (lo + hi) >> 1;
      if (tid == 0) s_comm[3] = 0;
      __syncthreads();
      for (unsigned i = tid; i < mid; i += 1024)
        if (fkey(src[i]) == T) atomicAdd(&s_comm[3], 1u);
      __syncthreads();
      unsigned c = s_comm[3];
      __syncthreads();
      if (c >= r) hi = mid; else lo = mid + 1;
    }
    m = lo;
  }
  if (tid == 0) s_comm[3] = 0;
  __syncthreads();
  for (int i = tid; i < N; i += 1024) {
    unsigned u = fkey(src[i]);
    if (u > T || (u == T && (unsigned)i < m)) {
      unsigned p = atomicAdd(&s_comm[3], 1u);
      if (p < 1024)
        keys[p] = ((unsigned long long)u << 32) | (unsigned)(~(unsigned)i);
    }
  }
  __syncthreads();
  if (tid >= k) keys[tid] = 0ull;  // pad; sorts to the end
  __syncthreads();
  // bitonic sort, descending
  for (unsigned k2 = 2; k2 <= 1024; k2 <<= 1) {
    for (unsigned j = k2 >> 1; j > 0; j >>= 1) {
      unsigned i = tid, ixj = i ^ j;
      if (ixj > i) {
        unsigned long long a = keys[i], b = keys[ixj];
        bool sw = ((i & k2) == 0) ? (a < b) : (a > b);
        if (sw) { keys[i] = b; keys[ixj] = a; }
      }
      __syncthreads();
    }
  }
  if (tid < k) {
    unsigned long long key = keys[tid];
    unsigned u = (unsigned)(key >> 32);
    unsigned idx = ~((unsigned)key);
    float sc = funkey(u);
    float4 b = bsrc[idx];
    if (FINAL) {
      float* o = finalOut + ((size_t)img * 1000 + tid) * 5;
      o[0] = b.x; o[1] = b.y; o[2] = b.z; o[3] = b.w; o[4] = sc;
    } else {
      scoresOut[(size_t)img * ATOT_PER_IMG + c_AOFF[lvl] + tid] = sc;
      boxesOut[(size_t)img * ATOT_PER_IMG + c_AOFF[lvl] + tid] = b;
    }
  }
}

// ------------------------------ NMS ----------------------------------------
__global__ __launch_bounds__(256) void nms_matrix(
    const float4* __restrict__ allb, unsigned long long* __restrict__ supp) {
  int lvl = blockIdx.x, img = blockIdx.y, rb = blockIdx.z;
  int k = c_KLVL[lvl];
  int task = img * 5 + lvl;
  const float4* src = allb + (size_t)img * ATOT_PER_IMG + c_AOFF[lvl];
  __shared__ float4 bb[1000];
  __shared__ float ar[1000];
  for (int j = threadIdx.x; j < k; j += 256) {
    float4 b = src[j];
    bb[j] = b;
    ar[j] = __fmul_rn(__fsub_rn(b.z, b.x), __fsub_rn(b.w, b.y));
  }
  __syncthreads();
  int i = rb * 256 + threadIdx.x;
  if (i < k) {
    float4 bi = bb[i];
    float ai = ar[i];
    unsigned long long* row = supp + ((size_t)task * 1024 + i) * 16;
    int jw0 = i >> 6;
    for (int jw = 0; jw < jw0; jw++) row[jw] = 0ull;
    for (int jw = jw0; jw < 16; jw++) {
      unsigned long long bits = 0;
      int jbase = jw * 64;
      for (int jj = 0; jj < 64; jj++) {
        int j = jbase + jj;
        if (j > i && j < k) {
          float4 bj = bb[j];
          float ltx = fmaxf(bi.x, bj.x), lty = fmaxf(bi.y, bj.y);
          float rbx = fminf(bi.z, bj.z), rby = fminf(bi.w, bj.w);
          float wx = fmaxf(__fsub_rn(rbx, ltx), 0.f);
          float wy = fmaxf(__fsub_rn(rby, lty), 0.f);
          float inter = __fmul_rn(wx, wy);
          float den = __fadd_rn(__fsub_rn(__fadd_rn(ai, ar[j]), inter), 1e-9f);
          if (__fdiv_rn(inter, den) > 0.7f) bits |= 1ull << jj;
        }
      }
      row[jw] = bits;
    }
  }
}

__global__ __launch_bounds__(64) void nms_scan(
    const float* __restrict__ topS, const unsigned long long* __restrict__ supp,
    float* __restrict__ fscore) {
  int lvl = blockIdx.x, img = blockIdx.y;
  int k = c_KLVL[lvl];
  int task = img * 5 + lvl;
  int lane = threadIdx.x;
  const unsigned long long* base = supp + (size_t)task * 1024 * 16;
  unsigned long long rem = 0, keep = 0;  // lane l<16 holds 64-bit word l
  for (int b0 = 0; b0 < k; b0 += 16) {
    unsigned long long buf[16];
#pragma unroll
    for (int t = 0; t < 16; t++) {
      int i = b0 + t;
      buf[t] = (lane < 16 && i < k) ? base[(size_t)i * 16 + lane] : 0ull;
    }
#pragma unroll
    for (int t = 0; t < 16; t++) {
      int i = b0 + t;
      if (i >= k) break;
      int wi = i >> 6, bi = i & 63;
      unsigned long long rw = __shfl(rem, wi);
      if (!((rw >> bi) & 1ull)) {  // i survives: suppress its row
        rem |= buf[t];
        if (lane == wi) keep |= (1ull << bi);
      }
    }
  }
  const float* ts = topS + (size_t)img * ATOT_PER_IMG + c_AOFF[lvl];
  float* fs = fscore + (size_t)img * ATOT_PER_IMG + c_AOFF[lvl];
  for (int i = lane; i < k; i += 64) {
    int wi = i >> 6;
    unsigned long long kw = __shfl(keep, wi);
    fs[i] = ((kw >> (i & 63)) & 1ull) ? ts[i] : -1e9f;
  }
}

// ------------------------------ host ---------------------------------------
static Anch mkAnch(double size) {
  Anch a;
  const double R[3] = {0.5, 1.0, 2.0};
  for (int i = 0; i < 3; i++) {
    double w = size * sqrt(1.0 / R[i]);
    double h = size * sqrt(R[i]);
    a.cx1[i] = (float)(-w / 2.0);
    a.cy1[i] = (float)(-h / 2.0);
  }
  return a;
}

extern "C" void kernel_launch(void* const* d_in, const int* in_sizes, int n_in,
                              void* d_out, int out_size, void* d_ws,
                              size_t ws_size, hipStream_t stream) {
  (void)in_sizes; (void)n_in; (void)out_size; (void)ws_size;
  const float* f0 = (const float*)d_in[0];
  const float* f1 = (const float*)d_in[1];
  const float* f2 = (const float*)d_in[2];
  const float* f3 = (const float*)d_in[3];
  const float* f4 = (const float*)d_in[4];
  const float* conv_w = (const float*)d_in[5];
  const float* conv_b = (const float*)d_in[6];
  const float* cls_w  = (const float*)d_in[7];
  const float* cls_b  = (const float*)d_in[8];
  const float* bbox_w = (const float*)d_in[9];
  const float* bbox_b = (const float*)d_in[10];
  float* out = (float*)d_out;

  // workspace layout (floats), all 16B-aligned; total ~14.4 MB
  float* wsf = (float*)d_ws;
  float* Wt     = wsf;                      // 589824
  float* scores = Wt + 589824;              // 2*261888
  float* boxes  = scores + 2 * NTOT_PER_IMG;       // 2*261888*4
  float* topS   = boxes + (size_t)2 * NTOT_PER_IMG * 4;  // 2*4768
  float* allb   = topS + 2 * ATOT_PER_IMG;         // 2*4768*4
  float* fscore = allb + (size_t)2 * ATOT_PER_IMG * 4;   // 2*4768
  unsigned long long* supp =
      (unsigned long long*)(fscore + 2 * ATOT_PER_IMG);  // 10*1024*16 u64

  wtrans<<<dim3(144, 16), 256, 0, stream>>>(conv_w, Wt);

  ConvCfg cfg;
  const double SZ[5] = {32, 64, 128, 256, 512};
  for (int l = 0; l < 5; l++) cfg.an[l] = mkAnch(SZ[l]);

  conv_gemm<<<2728, 256, 0, stream>>>(f0, f1, f2, f3, f4, Wt, conv_b, cls_w,
                                      cls_b, bbox_w, bbox_b, scores,
                                      (float4*)boxes, cfg);

  topk_kernel<false><<<dim3(5, 2), 1024, 0, stream>>>(
      scores, (const float4*)boxes, topS, (float4*)allb, nullptr);
  nms_matrix<<<dim3(5, 2, 4), 256, 0, stream>>>((const float4*)allb, supp);
  nms_scan<<<dim3(5, 2), 64, 0, stream>>>(topS, supp, fscore);
  topk_kernel<true><<<2, 1024, 0, stream>>>(
      fscore, (const float4*)allb, nullptr, nullptr, out);
}